// Round 8
// baseline (451.988 us; speedup 1.0000x reference)
//
#include <hip/hip_runtime.h>
#include <cstdint>
#include <cstddef>

// Problem constants
#define B_  16
#define T_  2048
#define DIN 1024
#define DPJ 512
#define DOUT 1024
#define LORD 20
#define HALO (LORD - 1)             // 19
#define M_ROWS (B_ * T_)            // 32768
#define OUT0_ELEMS ((size_t)M_ROWS * DOUT)          // 33554432

typedef __bf16 bf16_t;
typedef __bf16 bf16x2 __attribute__((ext_vector_type(2)));
typedef __bf16 bf16x4 __attribute__((ext_vector_type(4)));
typedef __bf16 bf16x8 __attribute__((ext_vector_type(8)));
typedef float  f32x4  __attribute__((ext_vector_type(4)));

#define SBAR __builtin_amdgcn_sched_barrier(0)

// ---------------------------------------------------------------------------
// async global->LDS, 16B per lane. lds pointer must be wave-uniform; HW puts
// lane i's 16B at lds_base + i*16.
__device__ __forceinline__ void async_load16(const void* g, void* lds_base) {
    __builtin_amdgcn_global_load_lds(
        (const __attribute__((address_space(1))) unsigned int*)g,
        (__attribute__((address_space(3))) unsigned int*)lds_base,
        16, 0, 0);
}

// ---------------------------------------------------------------------------
// XCD-aware bijective block swizzle (T1). Round-1 evidence: FETCH_SIZE
// 265MB -> 74MB on gemm1. Requires nwg % 8 == 0 (1024/2048 here).
__device__ __forceinline__ int xcd_swizzle(int hw, int nwg) {
    int cpx = nwg >> 3;                  // chunk per XCD
    return (hw & 7) * cpx + (hw >> 3);
}

// ---------------------------------------------------------------------------
// FUSED GEMM1 + depthwise conv + residual.  (prep_weights eliminated in
// round-8: B is reg-staged directly from untransposed W_lin with fused
// f32->bf16 cast — 16 strided L2-resident loads + 2 swizzled ds_write_b128
// per thread per K-step.  No global_load_lds left in this kernel; all
// waits are compiler-auto data-dep waits on one-phase-old loads, raw
// barriers keep them in flight.)
#define XR 160          // LDS x rows (t0-32 .. t0+127)
#define PADC 136        // padded channel stride for conv-phase LDS
__global__ __launch_bounds__(512, 4) void gemm1_conv(
    const float* __restrict__ A, const float* __restrict__ Wl,
    const float* __restrict__ cache, const float* __restrict__ cw,
    bf16_t* __restrict__ m, float* __restrict__ oc) {
    // LDS carve (72 KB): staging dbuf while K-loop runs; x-tile after.
    __shared__ __align__(16) char ldsraw[73728];
    bf16_t* sA0 = (bf16_t*)(ldsraw);            // 160*64*2 = 20480
    bf16_t* sA1 = (bf16_t*)(ldsraw + 20480);    // 20480
    bf16_t* sB0 = (bf16_t*)(ldsraw + 40960);    // 128*64*2 = 16384
    bf16_t* sB1 = (bf16_t*)(ldsraw + 57344);    // 16384 -> 73728
    bf16_t* xb  = (bf16_t*)(ldsraw);            // [160][136] = 43520 (aliases)

    const int tid  = threadIdx.x;
    const int lane = tid & 63;
    const int wave = tid >> 6;           // 0..7
    const int K    = DIN;

    const int gx   = gridDim.x;          // 4
    const int hw   = blockIdx.y * gx + blockIdx.x;
    const int lid  = xcd_swizzle(hw, gx * gridDim.y);
    const int lby  = lid / gx;           // M tile 0..255
    const int lbx  = lid - lby * gx;
    const int col0 = lbx * 128;          // channel tile
    const int b    = lby >> 4;           // batch
    const int tloc = (lby & 15) * 128;   // t0 within batch
    const float* Ab = A + (size_t)b * T_ * DIN;

    // ---- A staging: 5 f32x4 units/thread (rows 0..159 x 64 k f32) ----
    size_t aoff[5];
    int    doff[5];
#pragma unroll
    for (int i = 0; i < 5; ++i) {
        int u = tid + 512 * i;
        int r = u >> 4, c16 = u & 15;
        int t = tloc - 32 + r; if (t < 0) t = 0;
        aoff[i] = (size_t)t * DIN + c16 * 4;
        doff[i] = r * 64 + (((c16 >> 1) ^ (r & 7)) << 3) + (c16 & 1) * 4;
    }

    // ---- B staging from W_lin directly (transpose + cast in-kernel) ----
    // thread -> (bn = n row 0..127, bkg = chunk pair {bkg,bkg+1}); reads
    // Wl[k0+bkg*8+c][col0+bn] (16 consecutive-n lanes = 64B segments, Wl
    // slice is L2-resident); writes 2 swizzled ds_write_b128.
    const int bn  = tid >> 2;            // 0..127
    const int bkg = (tid & 3) * 2;       // chunks bkg, bkg+1
    const float* gW = Wl + (size_t)(bkg * 8) * DPJ + col0 + bn;
    const int bo0 = bn * 64 + ((bkg       ^ (bn & 7)) << 3);
    const int bo1 = bn * 64 + (((bkg + 1) ^ (bn & 7)) << 3);

    // compute-side: wave -> 80x32 sub-tile (2M x 4N), M extent 160
    const int wm = (wave >> 2) * 80;
    const int wn = (wave & 3) * 32;
    const int fr = lane & 15;
    const int fk = lane >> 4;

    const f32x4 zero = {0.f, 0.f, 0.f, 0.f};
    f32x4 acc[5][2];
#pragma unroll
    for (int mt = 0; mt < 5; ++mt)
#pragma unroll
        for (int nt = 0; nt < 2; ++nt) acc[mt][nt] = zero;

    f32x4 P[5];
    float bb[16];
    auto load_a = [&](int kk) {
#pragma unroll
        for (int i = 0; i < 5; ++i) P[i] = *(const f32x4*)(Ab + aoff[i] + kk);
    };
    auto load_b = [&](int kk) {
#pragma unroll
        for (int c = 0; c < 16; ++c) bb[c] = gW[(size_t)(kk + c) * DPJ];
    };
    auto cvt_write_a = [&](bf16_t* dst) {
#pragma unroll
        for (int i = 0; i < 5; ++i) {
            bf16x4 v = { (bf16_t)P[i][0], (bf16_t)P[i][1],
                         (bf16_t)P[i][2], (bf16_t)P[i][3] };
            *(bf16x4*)(dst + doff[i]) = v;
        }
    };
    auto cvt_write_b = [&](bf16_t* dst) {
        bf16x8 v0 = { (bf16_t)bb[0], (bf16_t)bb[1], (bf16_t)bb[2], (bf16_t)bb[3],
                      (bf16_t)bb[4], (bf16_t)bb[5], (bf16_t)bb[6], (bf16_t)bb[7] };
        bf16x8 v1 = { (bf16_t)bb[8],  (bf16_t)bb[9],  (bf16_t)bb[10], (bf16_t)bb[11],
                      (bf16_t)bb[12], (bf16_t)bb[13], (bf16_t)bb[14], (bf16_t)bb[15] };
        *(bf16x8*)(dst + bo0) = v0;
        *(bf16x8*)(dst + bo1) = v1;
    };
    auto compute = [&](const bf16_t* bA, const bf16_t* bB) {
#pragma unroll
        for (int h = 0; h < 2; ++h) {
            bf16x8 af[5], bfr[2];
#pragma unroll
            for (int mt = 0; mt < 5; ++mt) {
                int r = wm + mt * 16 + fr;
                int j = h * 4 + fk;
                af[mt] = *(const bf16x8*)(bA + r * 64 + ((j ^ (r & 7)) << 3));
            }
#pragma unroll
            for (int nt = 0; nt < 2; ++nt) {
                int r = wn + nt * 16 + fr;
                int j = h * 4 + fk;
                bfr[nt] = *(const bf16x8*)(bB + r * 64 + ((j ^ (r & 7)) << 3));
            }
#pragma unroll
            for (int mt = 0; mt < 5; ++mt)
#pragma unroll
                for (int nt = 0; nt < 2; ++nt)
                    acc[mt][nt] = __builtin_amdgcn_mfma_f32_16x16x32_bf16(
                        af[mt], bfr[nt], acc[mt][nt], 0, 0, 0);
        }
    };

    // ---- prologue: tile0 -> buf0; tile1 loads -> regs ----
    load_a(0); load_b(0);
    cvt_write_a(sA0); cvt_write_b(sB0);
    load_a(64); load_b(64);

    for (int k0 = 0; k0 < K; k0 += 128) {
        // ---- even tile e: compute buf0, fill buf1 with tile e+1 ----
        asm volatile("s_waitcnt lgkmcnt(0)" ::: "memory");
        SBAR; __builtin_amdgcn_s_barrier(); SBAR;
        cvt_write_a(sA1);                // auto-waits P (one phase old)
        cvt_write_b(sB1);                // auto-waits bb (one phase old)
        if (k0 + 128 < K) { load_a(k0 + 128); load_b(k0 + 128); }
        asm volatile("s_waitcnt lgkmcnt(0)" ::: "memory");
        SBAR; __builtin_amdgcn_s_barrier(); SBAR;
        compute(sA0, sB0);

        // ---- odd tile e+1: compute buf1, fill buf0 with tile e+2 ----
        asm volatile("s_waitcnt lgkmcnt(0)" ::: "memory");
        SBAR; __builtin_amdgcn_s_barrier(); SBAR;
        if (k0 + 128 < K) {
            cvt_write_a(sA0); cvt_write_b(sB0);
            if (k0 + 192 < K) { load_a(k0 + 192); load_b(k0 + 192); }
        }
        asm volatile("s_waitcnt lgkmcnt(0)" ::: "memory");
        SBAR; __builtin_amdgcn_s_barrier(); SBAR;
        compute(sA1, sB1);
    }

    // ================= fused conv epilogue (unchanged from r7) =============
    __syncthreads();     // all LDS staging reads done; safe to overwrite
    {
        const int er_l = wm + (lane >> 4) * 4;
        const int ec_l = wn + (lane & 15);
#pragma unroll
        for (int mt = 0; mt < 5; ++mt)
#pragma unroll
            for (int nt = 0; nt < 2; ++nt)
#pragma unroll
                for (int rr = 0; rr < 4; ++rr)
                    xb[(er_l + mt * 16 + rr) * PADC + ec_l + nt * 16] =
                        (bf16_t)acc[mt][nt][rr];
    }
    __syncthreads();

    // first-tile halo: rows 13..31 (t=-19..-1) <- in_cache[b][p][j]
    if (tloc == 0) {
        for (int i2 = tid; i2 < HALO * 128; i2 += 512) {
            int rr2 = i2 >> 7;            // 0..18
            int cc  = i2 & 127;
            xb[(13 + rr2) * PADC + cc] =
                (bf16_t)cache[((size_t)b * DPJ + col0 + cc) * HALO + rr2];
        }
    }
    __syncthreads();

    // conv + residual -> m.  Thread: 2 channels x 16 timesteps.
    {
        const int pp   = tid & 63;
        const int tb   = (tid >> 6) * 16;
        const int pg_l = 2 * pp;
        const int pg   = col0 + pg_l;

        float2 w[LORD];
#pragma unroll
        for (int l = 0; l < LORD; ++l) {
            w[l].x = cw[pg * LORD + l];
            w[l].y = cw[(pg + 1) * LORD + l];
        }
        auto rdx = [&](int r) -> float2 {
            bf16x2 v = *(const bf16x2*)(xb + r * PADC + pg_l);
            float2 f; f.x = (float)v[0]; f.y = (float)v[1]; return f;
        };
        float2 win[LORD];
#pragma unroll
        for (int i = 0; i < HALO; ++i) win[i] = rdx(tb + 13 + i);
#pragma unroll
        for (int tl = 0; tl < 16; ++tl) {
            float2 nv = rdx(tb + 13 + tl + HALO);   // x[t]
            win[(tl + HALO) % LORD] = nv;
            float2 s = nv;                          // residual
#pragma unroll
            for (int l = 0; l < LORD; ++l) {
                float2 v = win[(tl + l) % LORD];
                s.x += w[l].x * v.x;
                s.y += w[l].y * v.y;
            }
            bf16x2 o = { (bf16_t)s.x, (bf16_t)s.y };
            *(bf16x2*)(m + ((size_t)(b * T_ + tloc + tb + tl)) * DPJ + pg) = o;
        }
    }

    // out_cache from last t-tile: oc[b][p][j] = x[b, T-19+j, p]
    if (tloc == T_ - 128) {
        for (int i2 = tid; i2 < 128 * HALO; i2 += 512) {
            int pl = i2 / HALO;
            int j  = i2 - pl * HALO;
            oc[((size_t)b * DPJ + col0 + pl) * HALO + j] =
                (float)xb[(141 + j) * PADC + pl];
        }
    }
}

// ---------------------------------------------------------------------------
// GEMM2: out = relu(m @ W_aff + b).  A (m, bf16) via async DMA; B reg-staged
// from untransposed W_aff in two 16-load halves (prep_weights eliminated).
// Issue order per step keeps the A-DMA for tile t+1 in flight across the
// barrier: [bb-h0 loads][cvt h0: auto-drains A-DMA(t) + bb-h0]
// [bb-h1 loads][A-DMA(t+1)][cvt h1: drains to bb-h1, keeps A-DMA(t+1)].
__global__ __launch_bounds__(256) void gemm_bt_relu(
    const bf16_t* __restrict__ A, const float* __restrict__ Wa,
    float* __restrict__ C, const float* __restrict__ bias) {
    __shared__ bf16_t sA[2][128 * 64];
    __shared__ bf16_t sB[2][128 * 64];

    const int tid  = threadIdx.x;
    const int lane = tid & 63;
    const int wave = tid >> 6;           // 0..3
    const int K    = DPJ;                // 512
    const int N    = DOUT;               // 1024

    const int gx   = gridDim.x;          // 8
    const int hw   = blockIdx.y * gx + blockIdx.x;
    const int lid  = xcd_swizzle(hw, gx * gridDim.y);
    const int lby  = lid / gx;
    const int lbx  = lid - lby * gx;
    const int col0 = lbx * 128;          // N tile
    const int row0 = lby * 128;          // M tile

    // A staging (async DMA, k-contiguous bf16)
    const int lr   = lane >> 3;
    const int jsw  = (lane & 7) ^ lr;
    const bf16_t* gA0 = A + (size_t)(row0 + wave * 32 + lr) * K + jsw * 8;

    // B staging from Wa: thread -> (bn 0..127, bkg = 4 chunks bkg..bkg+3)
    const int bn  = tid >> 1;            // 0..127
    const int bkg = (tid & 1) * 4;       // chunks bkg..bkg+3
    const float* gW = Wa + (size_t)(bkg * 8) * DOUT + col0 + bn;
    int bo[4];
#pragma unroll
    for (int j = 0; j < 4; ++j)
        bo[j] = bn * 64 + (((bkg + j) ^ (bn & 7)) << 3);

    const int wm = (wave >> 1) * 64;
    const int wn = (wave & 1) * 64;
    const int fr = lane & 15;
    const int fk = lane >> 4;

    const f32x4 zero = {0.f, 0.f, 0.f, 0.f};
    f32x4 acc[4][4];
#pragma unroll
    for (int mt = 0; mt < 4; ++mt)
#pragma unroll
        for (int nt = 0; nt < 4; ++nt) acc[mt][nt] = zero;

    float bb[16];
    auto stage_a = [&](int kk, bf16_t* dA) {
#pragma unroll
        for (int c = 0; c < 4; ++c)
            async_load16(gA0 + (size_t)c * 8 * K + kk, dA + wave * 2048 + c * 512);
    };
    auto load_b_half = [&](int kk, int h) {
#pragma unroll
        for (int c = 0; c < 16; ++c)
            bb[c] = gW[(size_t)(kk + h * 16 + c) * DOUT];
    };
    auto cvt_write_b_half = [&](bf16_t* dst, int h) {
        bf16x8 v0 = { (bf16_t)bb[0], (bf16_t)bb[1], (bf16_t)bb[2], (bf16_t)bb[3],
                      (bf16_t)bb[4], (bf16_t)bb[5], (bf16_t)bb[6], (bf16_t)bb[7] };
        bf16x8 v1 = { (bf16_t)bb[8],  (bf16_t)bb[9],  (bf16_t)bb[10], (bf16_t)bb[11],
                      (bf16_t)bb[12], (bf16_t)bb[13], (bf16_t)bb[14], (bf16_t)bb[15] };
        *(bf16x8*)(dst + bo[h * 2])     = v0;
        *(bf16x8*)(dst + bo[h * 2 + 1]) = v1;
    };
    auto compute = [&](const bf16_t* bA, const bf16_t* bB) {
#pragma unroll
        for (int h = 0; h < 2; ++h) {
            bf16x8 af[4], bfr[4];
#pragma unroll
            for (int mt = 0; mt < 4; ++mt) {
                int r = wm + mt * 16 + fr;
                int j = h * 4 + fk;
                af[mt] = *(const bf16x8*)(bA + r * 64 + ((j ^ (r & 7)) << 3));
            }
#pragma unroll
            for (int nt = 0; nt < 4; ++nt) {
                int r = wn + nt * 16 + fr;
                int j = h * 4 + fk;
                bfr[nt] = *(const bf16x8*)(bB + r * 64 + ((j ^ (r & 7)) << 3));
            }
#pragma unroll
            for (int mt = 0; mt < 4; ++mt)
#pragma unroll
                for (int nt = 0; nt < 4; ++nt)
                    acc[mt][nt] = __builtin_amdgcn_mfma_f32_16x16x32_bf16(
                        af[mt], bfr[nt], acc[mt][nt], 0, 0, 0);
        }
    };

    // prologue: tile 0 -> buf0
    stage_a(0, sA[0]);                    // A-DMA(0) first (oldest)
    load_b_half(0, 0); cvt_write_b_half(sB[0], 0);   // drains A-DMA(0) too
    load_b_half(0, 1); cvt_write_b_half(sB[0], 1);

    for (int k0 = 0; k0 < K; k0 += 128) {
        // ---- even tile e: compute buf0, stage e+1 -> buf1 ----
        asm volatile("s_waitcnt lgkmcnt(0)" ::: "memory");
        SBAR; __builtin_amdgcn_s_barrier(); SBAR;
        {
            load_b_half(k0 + 64, 0);
            cvt_write_b_half(sB[1], 0);   // drains bb-h0 (+ older A-DMA(e))
            load_b_half(k0 + 64, 1);
            stage_a(k0 + 64, sA[1]);      // A-DMA(e+1), newer than bb-h1
            cvt_write_b_half(sB[1], 1);   // drains to bb-h1, keeps A-DMA(e+1)
        }
        asm volatile("s_waitcnt lgkmcnt(0)" ::: "memory");
        SBAR; __builtin_amdgcn_s_barrier(); SBAR;
        compute(sA[0], sB[0]);

        // ---- odd tile o=e+1: compute buf1, stage o+1 -> buf0 ----
        asm volatile("s_waitcnt lgkmcnt(0)" ::: "memory");
        SBAR; __builtin_amdgcn_s_barrier(); SBAR;
        if (k0 + 128 < K) {
            load_b_half(k0 + 128, 0);
            cvt_write_b_half(sB[0], 0);   // drains A-DMA(o)
            load_b_half(k0 + 128, 1);
            stage_a(k0 + 128, sA[0]);
            cvt_write_b_half(sB[0], 1);
        } else {
            asm volatile("s_waitcnt vmcnt(0)" ::: "memory");  // drain A-DMA(7)
        }
        asm volatile("s_waitcnt lgkmcnt(0)" ::: "memory");
        SBAR; __builtin_amdgcn_s_barrier(); SBAR;
        compute(sA[1], sB[1]);
    }

    const int er = row0 + wm + (lane >> 4) * 4;
    const int ec = col0 + wn + (lane & 15);
#pragma unroll
    for (int nt = 0; nt < 4; ++nt) {
        float bbias = bias[ec + nt * 16];
#pragma unroll
        for (int mt = 0; mt < 4; ++mt)
#pragma unroll
            for (int rr = 0; rr < 4; ++rr) {
                float v = acc[mt][nt][rr] + bbias;
                C[(size_t)(er + mt * 16 + rr) * N + (ec + nt * 16)] =
                    v > 0.f ? v : 0.f;
            }
    }
}

// ---------------------------------------------------------------------------
extern "C" void kernel_launch(void* const* d_in, const int* in_sizes, int n_in,
                              void* d_out, int out_size, void* d_ws, size_t ws_size,
                              hipStream_t stream) {
    const float* input    = (const float*)d_in[0];  // (16,2048,1024)
    const float* in_cache = (const float*)d_in[1];  // (16,512,19)
    const float* W_lin    = (const float*)d_in[2];  // (1024,512)
    const float* conv_w   = (const float*)d_in[3];  // (512,20)
    const float* W_aff    = (const float*)d_in[4];  // (512,1024)
    const float* b_aff    = (const float*)d_in[5];  // (1024,)
    float* out = (float*)d_out;                     // 33554432 + 155648 f32

    // workspace: [32MB, 64MB) m bf16 (32768x512).  (WlT/WaT gone.)
    char* ws = (char*)d_ws;
    bf16_t* m_buf = (bf16_t*)(ws + 33554432);

    // 1. fused: x = bf16(input) @ W_lin ; depthwise conv + residual -> m ;
    //    out_cache from last-t blocks.  B transposed+cast in staging.
    gemm1_conv<<<dim3(DPJ / 128, M_ROWS / 128), 512, 0, stream>>>(
        input, W_lin, in_cache, conv_w, m_buf, out + OUT0_ELEMS);

    // 2. out = relu(m @ W_aff + b).  B transposed+cast in staging.
    gemm_bt_relu<<<dim3(DOUT / 128, M_ROWS / 128), 256, 0, stream>>>(
        m_buf, W_aff, out, b_aff);
}